// Round 1
// 565.466 us; speedup vs baseline: 1.0324x; 1.0324x over previous
//
#include <hip/hip_runtime.h>

// ---------------------------------------------------------------------------
// TFN forward, 3-dispatch pipeline:
//  k1: encoders (direct strided weight reads, no pre-transpose) -> a1T/v1T/t1T
//      [97(98)][64] fp32 transposed (row0 = ones); wg288 zeroes t1T row97 and
//      the Y1SUM accumulator.
//  k3: y1-sum = fusion @ W1 via bf16 MFMA. W1 (350 MB) streamed exactly once
//      via global_load_lds into a 4-buffer depth-3 pipeline with counted
//      s_waitcnt vmcnt(6) + raw s_barrier (no vmcnt(0) drain in the K-loop).
//      s[run][b] and t1 bf16 pair-packing are computed in the prologue
//      (k2 eliminated). Partials accumulated with fp32 atomicAdd
//      (k4a eliminated). Grid 512 = exactly 2 wg/CU; contiguous group ranges.
//  k5: y1 = relu(Y1SUM+b1); features = relu(y1@W2+b2); heads; interloss.
//
// vmcnt bookkeeping: every stage is uniformly 3 global_load_lds per wave
// (the k=96 tail stages a full 8-row block with per-lane address clamp to
// W1's end; rows 97..103 are killed by the zero t1 pairs, values stay finite).
// ---------------------------------------------------------------------------

typedef unsigned int u32;
typedef short frag8s __attribute__((ext_vector_type(8)));   // 8 bf16 in 4 VGPRs
typedef float f32x4 __attribute__((ext_vector_type(4)));

constexpr int NRUN   = 9409;           // 97*97 (i,j) runs
constexpr int NGROUP = 2353;           // ceil(9409/4)
constexpr int RBLK   = 776;            // LDS floats per run-block (768 + 8 pad)
constexpr int NW1    = 912673 * 96;    // W1 element count (87,616,608)
constexpr int G3     = 512;            // main kernel grid (2 wg/CU exactly)

// workspace layout (float-element offsets) — ~100 KB total
constexpr int WS_A1T   = 0;                      // 98*64
constexpr int WS_V1T   = WS_A1T + 98 * 64;
constexpr int WS_T1T   = WS_V1T + 98 * 64;       // row 97 zeroed (pair padding)
constexpr int WS_Y1SUM = WS_T1T + 98 * 64;       // 64*96 fp32, zeroed by k1

__device__ __forceinline__ u32 bfrne(float x) {          // fp32 -> bf16 RNE
    u32 u = __float_as_uint(x);
    return (u + 0x7FFFu + ((u >> 16) & 1u)) >> 16;
}
__device__ __forceinline__ float bflo(u32 p) { return __uint_as_float(p << 16); }
__device__ __forceinline__ float bfhi(u32 p) { return __uint_as_float(p & 0xFFFF0000u); }

__device__ __forceinline__ void async_cp16(float* lds, const float* g) {
    __builtin_amdgcn_global_load_lds((const __attribute__((address_space(1))) u32*)g,
                                     (__attribute__((address_space(3))) u32*)lds, 16, 0, 0);
}

// ---------------- k1: encoders (wave-per-row dot + shfl reduce) ----------------
// Weights read directly (stride-96 columns); total weight bytes = 786 KB, L2
// absorbs line re-reads — cheaper than the old transpose kernel + round trip.
__global__ __launch_bounds__(256) void k1_enc(const float* __restrict__ audios,
                                              const float* __restrict__ texts,
                                              const float* __restrict__ videos,
                                              const float* __restrict__ Wa, const float* __restrict__ ba,
                                              const float* __restrict__ Wt, const float* __restrict__ bt,
                                              const float* __restrict__ Wv, const float* __restrict__ bv,
                                              float* __restrict__ ws) {
    int wg = blockIdx.x, tid = threadIdx.x;
    int lane = tid & 63, wv = tid >> 6;
    if (wg == 288) {                      // utility wg: zero t1T row 97 + Y1SUM
        if (tid < 64) ws[WS_T1T + 97 * 64 + tid] = 0.0f;
        for (int i = tid; i < 6144; i += 256) ws[WS_Y1SUM + i] = 0.0f;
        return;
    }
    int e = wg / 96, h = wg % 96;
    const float* in; const float* W; float bias; int K; int outbase;
    if (e == 0)      { in = audios; W = Wa; bias = ba[h]; K = 512;  outbase = WS_A1T; }
    else if (e == 1) { in = texts;  W = Wt; bias = bt[h]; K = 1024; outbase = WS_T1T; }
    else             { in = videos; W = Wv; bias = bv[h]; K = 512;  outbase = WS_V1T; }
    int nsweep = K >> 8;                  // 2 or 4 sweeps of 256 k per lane-pass
    float4 wreg[4];
    for (int s = 0; s < nsweep; s++) {
        int k0i = s * 256 + lane * 4;
        wreg[s] = make_float4(W[(k0i + 0) * 96 + h], W[(k0i + 1) * 96 + h],
                              W[(k0i + 2) * 96 + h], W[(k0i + 3) * 96 + h]);
    }
    for (int pass = 0; pass < 16; pass++) {
        int b = pass * 4 + wv;
        float acc = 0.f;
        for (int s = 0; s < nsweep; s++) {
            float4 iv = ((const float4*)(in + b * K))[s * 64 + lane];
            acc += iv.x * wreg[s].x + iv.y * wreg[s].y + iv.z * wreg[s].z + iv.w * wreg[s].w;
        }
        for (int off = 32; off; off >>= 1) acc += __shfl_down(acc, off, 64);
        if (lane == 0) {
            float v = acc + bias;
            ws[outbase + (h + 1) * 64 + b] = v > 0.f ? v : 0.f;
        }
    }
    if (h == 0 && tid < 64) ws[outbase + tid] = 1.0f;   // leading-ones row
}

// ---------------- k3: the 350 MB streaming MFMA kernel ----------------
// Per wg: 4 waves, 64 batch rows x 96 h. Wave w owns rows [16w,16w+16).
// K-step = 32 = 4 runs x 8 k (MFMA k-group q = lane>>4 selects run).
// 4 LDS W-buffers, depth-3 prefetch: stage(u+3) issued at step u;
// end-of-step: s_waitcnt vmcnt(6) (keeps u+2,u+3 in flight) + s_barrier.
// Buffer-reuse invariant: stage at top of u writes buf[(u+3)&3]=buf[(u-1)&3],
// whose readers all passed the barrier ending step u-1.
__global__ __launch_bounds__(256) void k3_main(const float* __restrict__ W1,
                                               float* __restrict__ ws) {
    __shared__ float wtile[4][4 * RBLK];    // 49664 B
    __shared__ u32   tpk[64 * 65];          // 16640 B (pad 65 for banks)
    __shared__ float sl[5][256];            // 5120 B: s for up to 5 groups

    int tid = threadIdx.x, lane = tid & 63, wv = tid >> 6;
    int id = blockIdx.x;
    // contiguous group ranges: 305 wgs x 5 groups + 207 wgs x 4 = 2353
    int g0, gcount;
    if (id < 305) { g0 = id * 5;                 gcount = 5; }
    else          { g0 = 1525 + (id - 305) * 4;  gcount = 4; }
    const int L = gcount * 13;              // total K-steps for this wg

    // ---- prologue: t1 bf16 pair packing (k2's job, per-wg from L2) ----
    for (int i = tid; i < 4096; i += 256) {
        int b_ = i >> 6, p = i & 63;
        u32 v = 0;
        if (p < 49) {                       // rows 0..97 (row 97 zeroed by k1)
            float e0 = ws[WS_T1T + (2 * p) * 64 + b_];
            float e1 = ws[WS_T1T + (2 * p + 1) * 64 + b_];
            v = bfrne(e0) | (bfrne(e1) << 16);
        }
        tpk[b_ * 65 + p] = v;
    }
    // ---- prologue: s[run][b] for ALL groups of this wg (no loads in K-loop) ----
    {
        int q2 = tid >> 6, b_ = tid & 63;
#pragma unroll
        for (int g2 = 0; g2 < 5; g2++) {
            float s = 0.f;
            int run = (g0 + g2) * 4 + q2;
            if (g2 < gcount && run < NRUN) {
                int i = run / 97, j = run % 97;
                s = ws[WS_A1T + i * 64 + b_] * ws[WS_V1T + j * 64 + b_];
            }
            sl[g2][tid] = s;
        }
    }

    // uniform 3-load stage; per-lane address clamp keeps the tail in-bounds
    auto stage = [&](int g, int t, int buf) {
        int idx0 = (g * 4 + wv) * (97 * 96) + t * (8 * 96) + lane * 4;
        float* ldst = &wtile[buf][wv * RBLK];
#pragma unroll
        for (int c = 0; c < 3; c++) {
            int idx = idx0 + c * 256;
            idx = idx < NW1 - 4 ? idx : NW1 - 4;   // finite real-W fill; A=0 kills it
            async_cp16(ldst + c * 256, W1 + idx);
        }
    };
    int cs_g = g0, cs_t = 0;                 // staging cursor (sequential steps)
    auto stage_next = [&](int buf) {
        stage(cs_g, cs_t, buf);
        if (++cs_t == 13) { cs_t = 0; ++cs_g; }
    };

    stage_next(0); stage_next(1); stage_next(2);            // steps 0,1,2
    asm volatile("s_waitcnt vmcnt(6) lgkmcnt(0)" ::: "memory");  // step0 landed; tpk/sl published
    __builtin_amdgcn_s_barrier();

    f32x4 acc[6];
#pragma unroll
    for (int nt = 0; nt < 6; nt++) acc[nt] = f32x4{0.f, 0.f, 0.f, 0.f};

    int b = (wv << 4) + (lane & 15);      // A-frag row -> batch
    int q = lane >> 4;                    // k-group -> run select

    int gi = 0, t = 0;
    for (int u = 0; u < L; ++u) {
        if (u + 3 < L) stage_next((u + 3) & 3);   // depth-3 prefetch

        // A-frag: f[b, k] = s_run[b] * t1[b, t*8+j]  (RNE-packed bf16 pairs)
        float sv = sl[gi][q * 64 + b];
        int pb = b * 65 + t * 4;
        u32 ap[4];
#pragma unroll
        for (int r = 0; r < 4; r++) {
            u32 tp = tpk[pb + r];
            float fe = sv * bflo(tp), fo = sv * bfhi(tp);
            ap[r] = bfrne(fe) | (bfrne(fo) << 16);
        }
        union { u32 u4[4]; frag8s f; } afr;
        afr.u4[0] = ap[0]; afr.u4[1] = ap[1]; afr.u4[2] = ap[2]; afr.u4[3] = ap[3];

        // B-frags from wtile[u&3]; stride 776%32=8 -> 2 lanes/bank = free
        const float* wt0 = &wtile[u & 3][q * RBLK + (lane & 15)];
#pragma unroll
        for (int nt = 0; nt < 6; nt++) {
            union { u32 u4[4]; frag8s f; } bfr;
#pragma unroll
            for (int r = 0; r < 4; r++) {
                u32 w0 = __float_as_uint(wt0[(2 * r) * 96 + nt * 16]);
                u32 w1 = __float_as_uint(wt0[(2 * r + 1) * 96 + nt * 16]);
                bfr.u4[r] = (w0 >> 16) | (w1 & 0xFFFF0000u);   // bf16 truncate-pack
            }
            acc[nt] = __builtin_amdgcn_mfma_f32_16x16x32_bf16(afr.f, bfr.f, acc[nt], 0, 0, 0);
        }

        // counted wait: step u+1's stage (3 oldest of <=9 outstanding) must land;
        // u+2/u+3 stay in flight across the barrier.
        if (u + 4 <= L)      asm volatile("s_waitcnt vmcnt(6) lgkmcnt(0)" ::: "memory");
        else if (u + 3 == L) asm volatile("s_waitcnt vmcnt(3) lgkmcnt(0)" ::: "memory");
        else                 asm volatile("s_waitcnt vmcnt(0) lgkmcnt(0)" ::: "memory");
        __builtin_amdgcn_s_barrier();

        if (++t == 13) { t = 0; ++gi; }
    }

    // accumulate 64x96 fp32 tile (C layout: col=lane&15, row=(lane>>4)*4+r)
    float* ysum = ws + WS_Y1SUM;
#pragma unroll
    for (int nt = 0; nt < 6; nt++) {
#pragma unroll
        for (int r = 0; r < 4; r++) {
            int row = (wv << 4) + ((lane >> 4) << 2) + r;
            int col = nt * 16 + (lane & 15);
            atomicAdd(&ysum[row * 96 + col], acc[nt][r]);
        }
    }
}

// ---------------- k5: y1 finalize + features + heads (8 wgs, 8 rows each) ----------------
__global__ __launch_bounds__(256) void k5_final(const float* __restrict__ b1,
                                                const float* __restrict__ W2, const float* __restrict__ b2,
                                                const float* __restrict__ Wo1, const float* __restrict__ bo1,
                                                const float* __restrict__ Wo2, const float* __restrict__ bo2,
                                                const float* __restrict__ Wo3, const float* __restrict__ bo3,
                                                const float* __restrict__ ws, float* __restrict__ out) {
    __shared__ float yl[8 * 96];
    __shared__ float w2l[96 * 97];     // +1 pad
    __shared__ float fl[8 * 96];
    int tid = threadIdx.x;
    int row0 = blockIdx.x * 8;
    // y1 rows [row0, row0+8): atomically-accumulated sum + bias + relu
    for (int i = tid; i < 768; i += 256) {
        int go = row0 * 96 + i;
        float acc = b1[i % 96] + ws[WS_Y1SUM + go];
        yl[i] = acc > 0.f ? acc : 0.f;
    }
    for (int i = tid; i < 9216; i += 256) { int k = i / 96, h = i % 96; w2l[k * 97 + h] = W2[i]; }
    __syncthreads();
    for (int i = tid; i < 768; i += 256) {
        int bb = i / 96, h = i % 96;
        float acc = b2[h];
#pragma unroll 8
        for (int k = 0; k < 96; k++) acc += yl[bb * 96 + k] * w2l[k * 97 + h];
        float f = acc > 0.f ? acc : 0.f;
        fl[i] = f; out[(row0 + bb) * 96 + h] = f;
    }
    __syncthreads();
    // heads for rows [row0, row0+8): 48 + 8 + 24 = 80 outputs
    if (tid < 80) {
        if (tid < 48) {
            int lr = tid / 6, j = tid % 6;
            float acc = bo1[j];
            for (int k = 0; k < 96; k++) acc += fl[lr * 96 + k] * Wo1[k * 6 + j];
            out[6144 + (row0 + lr) * 6 + j] = acc;
        } else if (tid < 56) {
            int lr = tid - 48;
            float acc = bo2[0];
            for (int k = 0; k < 96; k++) acc += fl[lr * 96 + k] * Wo2[k];
            out[6528 + row0 + lr] = acc;
        } else {
            int t2 = tid - 56; int lr = t2 / 3, j = t2 % 3;
            float acc = bo3[j];
            for (int k = 0; k < 96; k++) acc += fl[lr * 96 + k] * Wo3[k * 3 + j];
            out[6592 + (row0 + lr) * 3 + j] = acc;
        }
    }
    if (blockIdx.x == 0 && tid == 0) out[6784] = 0.0f;    // interloss
}

extern "C" void kernel_launch(void* const* d_in, const int* in_sizes, int n_in,
                              void* d_out, int out_size, void* d_ws, size_t ws_size,
                              hipStream_t stream) {
    (void)in_sizes; (void)n_in; (void)out_size; (void)ws_size;
    const float* audios = (const float*)d_in[0];
    const float* texts  = (const float*)d_in[1];
    const float* videos = (const float*)d_in[2];
    const float* Wa  = (const float*)d_in[3];
    const float* ba  = (const float*)d_in[4];
    const float* Wt  = (const float*)d_in[5];
    const float* bt  = (const float*)d_in[6];
    const float* Wv  = (const float*)d_in[7];
    const float* bv  = (const float*)d_in[8];
    const float* W1  = (const float*)d_in[9];
    const float* b1  = (const float*)d_in[10];
    const float* W2  = (const float*)d_in[11];
    const float* b2  = (const float*)d_in[12];
    const float* Wo1 = (const float*)d_in[13];
    const float* bo1 = (const float*)d_in[14];
    const float* Wo2 = (const float*)d_in[15];
    const float* bo2 = (const float*)d_in[16];
    const float* Wo3 = (const float*)d_in[17];
    const float* bo3 = (const float*)d_in[18];
    float* ws = (float*)d_ws;
    float* outp = (float*)d_out;

    k1_enc<<<289, 256, 0, stream>>>(audios, texts, videos, Wa, ba, Wt, bt, Wv, bv, ws);
    k3_main<<<G3, 256, 0, stream>>>(W1, ws);
    k5_final<<<8, 256, 0, stream>>>(b1, W2, b2, Wo1, bo1, Wo2, bo2, Wo3, bo3, ws, outp);
}